// Round 3
// baseline (813.956 us; speedup 1.0000x reference)
//
#include <hip/hip_runtime.h>
#include <cstdint>
#include <cstddef>

#define HEADS 16
#define DH 64
#define BH 28
#define BWW 28
#define BATCH 32
#define HID 1024
#define M_ROWS 25088           // 32*28*28
#define ALPHA_C 0.082847664332725576f
#define EPS_C 1e-5f

typedef unsigned short ushort_t;
typedef __attribute__((ext_vector_type(8))) short bf16x8;     // 8 bf16 in 4 VGPRs
typedef __attribute__((ext_vector_type(4))) float f32x4;

__device__ inline unsigned short f2bf(float f) {
  unsigned int u = __builtin_bit_cast(unsigned int, f);
  u = (u + 0x7fffu + ((u >> 16) & 1u)) >> 16;   // RNE
  return (unsigned short)u;
}
__device__ inline float bf2f(unsigned short h) {
  unsigned int u = ((unsigned int)h) << 16;
  return __builtin_bit_cast(float, u);
}

// -------- dtype detect (bf16 vs fp32 bits) + zero stats --------
// bf16 interp of genuine bf16 data -> |v| small; of fp32 bit-halves -> wild exponents.
__global__ __launch_bounds__(256) void detect_k(const ushort_t* __restrict__ x,
                                                const ushort_t* __restrict__ qw,
                                                float* __restrict__ stats,
                                                int* __restrict__ flagp) {
  int tid = threadIdx.x;
  int big = 0;
  #pragma unroll
  for (int j = 0; j < 4; ++j) {
    float a = fabsf(bf2f(x[tid * 4 + j]));
    float b = fabsf(bf2f(qw[tid * 4 + j]));
    if (!(a < 1e3f)) big++;            // catches huge, Inf, NaN
    if (!(b < 1e3f)) big++;
  }
  __shared__ int cnt;
  if (tid == 0) cnt = 0;
  __syncthreads();
  if (big) atomicAdd(&cnt, big);
  __syncthreads();
  if (tid == 0) *flagp = (cnt == 0) ? 1 : 0;   // 1 = inputs are bf16
  stats[tid] = 0.f; stats[tid + 256] = 0.f; stats[tid + 512] = 0.f; stats[tid + 768] = 0.f;
}

// -------- canonicalize x -> bf16 (flag-branched) --------
__global__ __launch_bounds__(256) void conv_x_k(const void* __restrict__ src,
                                                const int* __restrict__ flagp,
                                                ushort_t* __restrict__ dst, long n8) {
  long i = (long)blockIdx.x * 256 + threadIdx.x;
  if (i >= n8) return;
  long e = i * 8;
  if (*flagp) {
    *(uint4*)(dst + e) = *(const uint4*)((const ushort_t*)src + e);
  } else {
    const float* sf = (const float*)src;
    float4 a = *(const float4*)(sf + e);
    float4 b = *(const float4*)(sf + e + 4);
    union { ushort_t u[8]; uint4 v; } o;
    o.u[0] = f2bf(a.x); o.u[1] = f2bf(a.y); o.u[2] = f2bf(a.z); o.u[3] = f2bf(a.w);
    o.u[4] = f2bf(b.x); o.u[5] = f2bf(b.y); o.u[6] = f2bf(b.z); o.u[7] = f2bf(b.w);
    *(uint4*)(dst + e) = o.v;
  }
}

// -------- transpose either dtype -> bf16: dst[c*R+r] = src[r*C+c] --------
__global__ void transpose_any_k(const void* __restrict__ src, const int* __restrict__ flagp,
                                ushort_t* __restrict__ dst, int R, int C) {
  __shared__ float tile[32][33];
  int isbf = *flagp;
  int c0 = blockIdx.x * 32, r0 = blockIdx.y * 32;
  int tx = threadIdx.x, ty = threadIdx.y;
  const ushort_t* sb = (const ushort_t*)src;
  const float* sf = (const float*)src;
  #pragma unroll
  for (int i = ty; i < 32; i += 8) {
    size_t idx = (size_t)(r0 + i) * C + (c0 + tx);
    tile[i][tx] = isbf ? bf2f(sb[idx]) : sf[idx];
  }
  __syncthreads();
  #pragma unroll
  for (int i = ty; i < 32; i += 8)
    dst[(size_t)(c0 + i) * R + (r0 + tx)] = f2bf(tile[tx][i]);
}

// -------- bf16 MFMA GEMM (m97 recipe): C[M,N] = A[M,K] * Bt[N,K]^T --------
// dynout=false: C is bf16. dynout=true: branch on flag (bf16 vs fp32 store).
#define BK 32
__global__ __launch_bounds__(256) void gemm_bt_k(const ushort_t* __restrict__ A,
                                                 const ushort_t* __restrict__ Bt,
                                                 void* __restrict__ Cv,
                                                 const int* __restrict__ flagp,
                                                 int dynout, int M, int N, int K) {
  __shared__ ushort_t As[128 * BK];
  __shared__ ushort_t Bs[128 * BK];
  const int tid = threadIdx.x;
  const int ntile = N / 128;
  const int n0 = (blockIdx.x % ntile) * 128;
  const int m0 = (blockIdx.x / ntile) * 128;
  const int lane = tid & 63;
  const int wave = tid >> 6;
  const int wm = (wave >> 1) * 64;
  const int wn = (wave & 1) * 64;
  const int fr = lane & 15;
  const int fq = lane >> 4;

  f32x4 acc[4][4] = {};
  const int srow = tid >> 2;
  const int skk  = (tid & 3) * 8;

  for (int k0 = 0; k0 < K; k0 += BK) {
    __syncthreads();
    const ushort_t* a0 = A + (size_t)(m0 + srow) * K + k0 + skk;
    const ushort_t* b0 = Bt + (size_t)(n0 + srow) * K + k0 + skk;
    __builtin_amdgcn_global_load_lds((const __attribute__((address_space(1))) unsigned int*)a0,
        (__attribute__((address_space(3))) unsigned int*)(As + tid * 8), 16, 0, 0);
    __builtin_amdgcn_global_load_lds((const __attribute__((address_space(1))) unsigned int*)(a0 + (size_t)64 * K),
        (__attribute__((address_space(3))) unsigned int*)(As + 2048 + tid * 8), 16, 0, 0);
    __builtin_amdgcn_global_load_lds((const __attribute__((address_space(1))) unsigned int*)b0,
        (__attribute__((address_space(3))) unsigned int*)(Bs + tid * 8), 16, 0, 0);
    __builtin_amdgcn_global_load_lds((const __attribute__((address_space(1))) unsigned int*)(b0 + (size_t)64 * K),
        (__attribute__((address_space(3))) unsigned int*)(Bs + 2048 + tid * 8), 16, 0, 0);
    __syncthreads();

    bf16x8 af[4], bfv[4];
    #pragma unroll
    for (int i = 0; i < 4; ++i)
      af[i] = *reinterpret_cast<const bf16x8*>(&As[(wm + i * 16 + fr) * BK + fq * 8]);
    #pragma unroll
    for (int i = 0; i < 4; ++i)
      bfv[i] = *reinterpret_cast<const bf16x8*>(&Bs[(wn + i * 16 + fr) * BK + fq * 8]);
    #pragma unroll
    for (int mi = 0; mi < 4; ++mi)
      #pragma unroll
      for (int ni = 0; ni < 4; ++ni)
        acc[mi][ni] = __builtin_amdgcn_mfma_f32_16x16x32_bf16(af[mi], bfv[ni], acc[mi][ni], 0, 0, 0);
  }

  // C/D layout: col=lane&15, row=fq*4+r (m89-verified)
  int isbf = dynout ? *flagp : 1;
  if (isbf) {
    ushort_t* C = (ushort_t*)Cv;
    #pragma unroll
    for (int mi = 0; mi < 4; ++mi)
      #pragma unroll
      for (int r = 0; r < 4; ++r) {
        int m = m0 + wm + mi * 16 + fq * 4 + r;
        ushort_t* crow = C + (size_t)m * N + n0 + wn + fr;
        #pragma unroll
        for (int ni = 0; ni < 4; ++ni) crow[ni * 16] = f2bf(acc[mi][ni][r]);
      }
  } else {
    float* C = (float*)Cv;
    #pragma unroll
    for (int mi = 0; mi < 4; ++mi)
      #pragma unroll
      for (int r = 0; r < 4; ++r) {
        int m = m0 + wm + mi * 16 + fq * 4 + r;
        float* crow = C + (size_t)m * N + n0 + wn + fr;
        #pragma unroll
        for (int ni = 0; ni < 4; ++ni) crow[ni * 16] = acc[mi][ni][r];
      }
  }
}

// -------- qkv post: +img*ALPHA, gamma on k, axial rope q/k (in place), vsum --------
__global__ __launch_bounds__(64) void qkv_post_k(ushort_t* __restrict__ qkv,
                                                 const void* __restrict__ img,
                                                 const int* __restrict__ flagp,
                                                 float* __restrict__ vsum) {
  int blk = blockIdx.x;
  int w = blk % BWW;
  int n = (blk / BWW) % HEADS;
  int b = blk / (BWW * HEADS);
  int d = threadIdx.x;
  int isbf = *flagp;
  const ushort_t* imgb = (const ushort_t*)img;
  const float* imgf = (const float*)img;

  float gamma = 1.0f - exp2f(-5.0f - (float)n);
  int fi = d & 15;
  float invf = powf(10000.0f, -(float)fi / 16.0f);
  float sgn = (d & 16) ? 1.0f : -1.0f;
  bool useH = (d < 32);
  float vacc = 0.0f;

  for (int h = 0; h < BH; ++h) {
    size_t m = ((size_t)b * BH + h) * BWW + w;
    size_t col = (size_t)n * DH + d;
    size_t ioff = m * HID + col;
    float iv = (isbf ? bf2f(imgb[ioff]) : imgf[ioff]) * ALPHA_C;
    ushort_t* qrow = qkv + m * (3 * HID);
    float qv = bf2f(qrow[col]) + iv;
    float vv = bf2f(qrow[HID + col]) + iv;
    float kv = (bf2f(qrow[2 * HID + col]) + iv) * gamma;
    vacc += vv;
    float pos = useH ? (float)h : (float)w;
    float ang = pos * invf;
    float sn, cs;
    __sincosf(ang, &sn, &cs);
    float qp = __shfl_xor(qv, 16);
    float kp = __shfl_xor(kv, 16);
    float qr = qv * cs + sgn * qp * sn;
    float kr = kv * cs + sgn * kp * sn;
    qrow[col] = f2bf(qr);
    qrow[2 * HID + col] = f2bf(kr);
  }
  vsum[(((size_t)b * HEADS + n) * BWW + w) * DH + d] = vacc;
}

// -------- attention per (b,n,h): S=Q K^T (28x28), out = S @ vsum --------
__global__ __launch_bounds__(256) void attn_k(const ushort_t* __restrict__ qkv,
                                              const float* __restrict__ vsum,
                                              ushort_t* __restrict__ out,
                                              float* __restrict__ stats) {
  __shared__ float Qs[BWW][DH + 1];
  __shared__ float Ks[BWW][DH + 1];
  __shared__ float Vs[BWW][DH + 1];
  __shared__ float Ss[BWW][BWW + 1];
  int blk = blockIdx.x;
  int h = blk % BH;
  int n = (blk / BH) % HEADS;
  int b = blk / (BH * HEADS);
  int tid = threadIdx.x;
  size_t obase = ((((size_t)b * HEADS + n) * BH + h) * BWW) * DH;
  size_t vbase = (((size_t)b * HEADS + n) * BWW) * DH;

  for (int e = tid; e < BWW * DH; e += 256) {
    int r = e / DH, c = e % DH;
    size_t m = ((size_t)b * BH + h) * BWW + r;
    size_t base = m * (3 * HID) + (size_t)n * DH + c;
    Qs[r][c] = bf2f(qkv[base]);
    Ks[r][c] = bf2f(qkv[base + 2 * HID]);
    Vs[r][c] = vsum[vbase + e];
  }
  __syncthreads();
  for (int e = tid; e < BWW * BWW; e += 256) {
    int x = e / BWW, z = e % BWW;
    float acc = 0.f;
    #pragma unroll
    for (int dd = 0; dd < DH; ++dd) acc += Qs[x][dd] * Ks[z][dd];
    Ss[x][z] = acc;
  }
  __syncthreads();
  float lsum = 0.f, lsq = 0.f;
  for (int e = tid; e < BWW * DH; e += 256) {
    int w = e / DH, dd = e % DH;
    float acc = 0.f;
    #pragma unroll
    for (int y = 0; y < BWW; ++y) acc += Ss[w][y] * Vs[y][dd];
    out[obase + e] = f2bf(acc);
    lsum += acc; lsq += acc * acc;
  }
  #pragma unroll
  for (int off = 32; off > 0; off >>= 1) {
    lsum += __shfl_down(lsum, off);
    lsq  += __shfl_down(lsq, off);
  }
  __shared__ float rs[4][2];
  int lane = tid & 63, wv = tid >> 6;
  if (lane == 0) { rs[wv][0] = lsum; rs[wv][1] = lsq; }
  __syncthreads();
  if (tid == 0) {
    float s  = rs[0][0] + rs[1][0] + rs[2][0] + rs[3][0];
    float q2 = rs[0][1] + rs[1][1] + rs[2][1] + rs[3][1];
    atomicAdd(&stats[(b * HEADS + n) * 2], s);
    atomicAdd(&stats[(b * HEADS + n) * 2 + 1], q2);
  }
}

// -------- GroupNorm apply + relayout to (b,H,W,hid) bf16 --------
__global__ __launch_bounds__(256) void gn_k(const ushort_t* __restrict__ out,
                                            const float* __restrict__ stats,
                                            const void* __restrict__ gn_w,
                                            const void* __restrict__ gn_b,
                                            const int* __restrict__ flagp,
                                            ushort_t* __restrict__ xo) {
  size_t idx = (size_t)blockIdx.x * 256 + threadIdx.x;   // (b,n,h,w,d)
  int d = idx & 63;
  size_t rest = idx >> 6;
  int w = rest % BWW; rest /= BWW;
  int h = rest % BH;  rest /= BH;
  int n = rest % HEADS;
  int b = (int)(rest / HEADS);
  int isbf = *flagp;
  float gw = isbf ? bf2f(((const ushort_t*)gn_w)[n]) : ((const float*)gn_w)[n];
  float gb = isbf ? bf2f(((const ushort_t*)gn_b)[n]) : ((const float*)gn_b)[n];
  float s  = stats[(b * HEADS + n) * 2];
  float q2 = stats[(b * HEADS + n) * 2 + 1];
  const float Ninv = 1.0f / (float)(BH * BWW * DH);
  float mu = s * Ninv;
  float var = q2 * Ninv - mu * mu;
  float rstd = rsqrtf(var + EPS_C);
  float v = (bf2f(out[idx]) - mu) * rstd * gw + gb;
  size_t dst = ((((size_t)b * BH + h) * BWW + w) * HID) + (size_t)n * DH + d;
  xo[dst] = f2bf(v);
}

// -------- launch --------
extern "C" void kernel_launch(void* const* d_in, const int* in_sizes, int n_in,
                              void* d_out, int out_size, void* d_ws, size_t ws_size,
                              hipStream_t stream) {
  const void* x     = d_in[0];
  const void* img   = d_in[1];
  const void* qkv_w = d_in[2];
  const void* o_w   = d_in[3];
  const void* gn_w  = d_in[4];
  const void* gn_b  = d_in[5];

  char* ws = (char*)d_ws;
  // layout (bytes), peak ~207.5 MiB (round-2-proven budget):
  ushort_t* qkv   = (ushort_t*)(ws);                 // 154,140,672; dead after attn_k
  ushort_t* xo    = (ushort_t*)(ws);                 // 51,380,224 — overlays dead qkv
  ushort_t* x_bf  = (ushort_t*)(ws + 154140672);     // 51,380,224; dead after gemm1
  ushort_t* attn  = (ushort_t*)(ws + 154140672);     // 51,380,224 — overlays dead x_bf
  float*    vsum  = (float*)(ws + 205520896);        //  3,670,016
  float*    stats = (float*)(ws + 209190912);        //      4,096
  int*      flag  = (int*)(ws + 209195008);          //        256
  ushort_t* w1T   = (ushort_t*)(ws + 209195264);     //  6,291,456
  ushort_t* w2T   = (ushort_t*)(ws + 215486720);     //  2,097,152 (end 217,583,872)

  detect_k<<<1, 256, 0, stream>>>((const ushort_t*)x, (const ushort_t*)qkv_w, stats, flag);
  conv_x_k<<<12544, 256, 0, stream>>>(x, flag, x_bf, 3211264L);
  transpose_any_k<<<dim3(96, 32), dim3(32, 8), 0, stream>>>(qkv_w, flag, w1T, 1024, 3072);
  transpose_any_k<<<dim3(32, 32), dim3(32, 8), 0, stream>>>(o_w, flag, w2T, 1024, 1024);

  gemm_bt_k<<<196 * 24, 256, 0, stream>>>(x_bf, w1T, qkv, flag, 0, M_ROWS, 3072, 1024);

  qkv_post_k<<<BATCH * HEADS * BWW, 64, 0, stream>>>(qkv, img, flag, vsum);
  attn_k<<<BATCH * HEADS * BH, 256, 0, stream>>>(qkv, vsum, attn, stats);
  gn_k<<<100352, 256, 0, stream>>>(attn, stats, gn_w, gn_b, flag, xo);

  gemm_bt_k<<<196 * 8, 256, 0, stream>>>(xo, w2T, d_out, flag, 1, M_ROWS, 1024, 1024);
}